// Round 2
// baseline (243.033 us; speedup 1.0000x reference)
//
#include <hip/hip_runtime.h>

typedef __bf16 bf16;
typedef __bf16 bf16x4 __attribute__((ext_vector_type(4)));
typedef __bf16 bf16x8 __attribute__((ext_vector_type(8)));
typedef float f32x4 __attribute__((ext_vector_type(4)));

#define LOG2E 1.44269504088896f

// async global->LDS, 16B per lane. LDS dest is wave-uniform base + lane*16
// (m104/m108): pass the lane-0 pointer; generic->AS(3) = low-32-bit truncation.
__device__ __forceinline__ void gl_lds16(const bf16* g, bf16* l) {
  __builtin_amdgcn_global_load_lds(
      reinterpret_cast<const __attribute__((address_space(1))) void*>((uintptr_t)g),
      reinterpret_cast<__attribute__((address_space(3))) void*>((uint32_t)(uintptr_t)l),
      16, 0, 0);
}

// ---------------- cast fp32 -> bf16 for weights + pm, and build RoPE cos/sin table ----------------
__global__ void cast3_kernel(const float* __restrict__ a, int na4, bf16* __restrict__ oa,
                             const float* __restrict__ b, int nb4, bf16* __restrict__ ob,
                             const float* __restrict__ c, int nc4, bf16* __restrict__ oc,
                             float2* __restrict__ tab, int nt) {
  int i = blockIdx.x * blockDim.x + threadIdx.x;
  if (i < na4 + nb4 + nc4) {
    const float* src; bf16* dst; int idx;
    if (i < na4)            { src = a; dst = oa; idx = i; }
    else if (i < na4 + nb4) { src = b; dst = ob; idx = i - na4; }
    else                    { src = c; dst = oc; idx = i - na4 - nb4; }
    float4 v = ((const float4*)src)[idx];
    bf16x4 o = { (bf16)v.x, (bf16)v.y, (bf16)v.z, (bf16)v.w };
    ((bf16x4*)dst)[idx] = o;
  } else {
    int idx = i - (na4 + nb4 + nc4);
    if (idx >= nt) return;
    int pos = idx >> 5, fi = idx & 31;
    float inv = exp2f((float)fi * -0.41524101186f);   // 10000^(-fi/32)
    float th = (float)pos * inv;
    float sn, cs;
    sincosf(th, &sn, &cs);
    tab[idx] = make_float2(cs, sn);
  }
}

// ---------------- RMSNorm: seq fp32 [8192][1024] -> x bf16 ----------------
__global__ __launch_bounds__(256) void rmsnorm_kernel(const float* __restrict__ seq,
                                                      const float* __restrict__ g,
                                                      bf16* __restrict__ xbf) {
  int row = blockIdx.x;
  int t = threadIdx.x;
  float4 x = ((const float4*)(seq + (size_t)row * 1024))[t];
  float ss = x.x*x.x + x.y*x.y + x.z*x.z + x.w*x.w;
  #pragma unroll
  for (int m = 32; m >= 1; m >>= 1) ss += __shfl_xor(ss, m, 64);
  __shared__ float red[4];
  if ((t & 63) == 0) red[t >> 6] = ss;
  __syncthreads();
  float tot = red[0] + red[1] + red[2] + red[3];
  float scale = rsqrtf(tot * (1.0f / 1024.0f) + 1.1920929e-07f);
  float4 gv = ((const float4*)g)[t];
  bf16x4 o = { (bf16)(x.x*scale*gv.x), (bf16)(x.y*scale*gv.y),
               (bf16)(x.z*scale*gv.z), (bf16)(x.w*scale*gv.w) };
  ((bf16x4*)(xbf + (size_t)row * 1024))[t] = o;
}

// ---------------- 128x256 8-wave deep-pipelined GEMM, C[M,N] = A[M,K] * B[N,K]^T ----------------
// Perfect grid packing: N/256 * M/128 blocks (768 for QKV = 3/CU, 256 for out-proj = 1/CU).
// Triple-buffered LDS (144 KiB): As[3][128][64], Bs[3][256][64]; tile t+2 staged during
// tile t (6 gl_lds16/tile: A x2 + B x4), one counted s_waitcnt vmcnt(6) per tile drains
// t+1's loads while t+2's stay in flight (m201 formula N = loads x depth = 6).
// 2 phases per K-tile, each: 8 ds_read_b128 + 3 gl_lds -> s_barrier -> setprio(1)
// 16 MFMA setprio(0) -> [vmcnt] -> s_barrier.  Requires nt = K/64 with nt%3==1, nt>=7.
// Buffer lifetimes: buf[(u+2)%3] holds tile u-1, last read before end-of-(u-1) barrier,
// restaged during tile u; buf[u%3] staged during u-2, drained by vmcnt(6)+barrier at end
// of u-1.  Tail: u=nt-2 drains vmcnt(0) before u=nt-1 reads.
template<int OUTF>
__global__ __launch_bounds__(512) void gemm128x256_kernel(const bf16* __restrict__ A,
                                                          const bf16* __restrict__ B,
                                                          void* __restrict__ C,
                                                          int M, int N, int K) {
  __shared__ bf16 As[3 * 8192];    // [buf][128 rows][64 k], XOR-swizzled chunks
  __shared__ bf16 Bs[3 * 16384];   // [buf][256 rows][64 k]
  int t = threadIdx.x;
  int lane = t & 63, wv = t >> 6;
  int m16 = lane & 15, quad = lane >> 4;
  int wr = (wv >> 2) * 64, wc = (wv & 3) * 64;   // 2M x 4N waves, per-wave C = 64x64
  int bn = blockIdx.x, bm = blockIdx.y;
  const bf16* Ab = A + (size_t)bm * 128 * K;
  const bf16* Bb = B + (size_t)bn * 256 * K;
  // per-lane pre-swizzled global source offsets: LDS chunk s (16B) of a tile holds
  // global k-chunk (s&7)^(row&7) of row s>>3 (row-major, 8 chunks of 8 bf16 per row).
  int aoff[2], boff[4];
  #pragma unroll
  for (int l = 0; l < 2; l++) { int s = l * 512 + t; int row = s >> 3; aoff[l] = row * K + ((s & 7) ^ (row & 7)) * 8; }
  #pragma unroll
  for (int l = 0; l < 4; l++) { int s = l * 512 + t; int row = s >> 3; boff[l] = row * K + ((s & 7) ^ (row & 7)) * 8; }
  f32x4 acc[4][4] = {};

#define STGA(BUF, T) { int k0 = (T) * 64; \
    gl_lds16(Ab + k0 + aoff[0], &As[(BUF) * 8192 + wv * 512]); \
    gl_lds16(Ab + k0 + aoff[1], &As[(BUF) * 8192 + 4096 + wv * 512]); }
#define STGB(BUF, T, L) { int k0 = (T) * 64; \
    gl_lds16(Bb + k0 + boff[L], &Bs[(BUF) * 16384 + (L) * 4096 + wv * 512]); }
#define VM6 asm volatile("s_waitcnt vmcnt(6)" ::: "memory");
#define VM0 asm volatile("s_waitcnt vmcnt(0)" ::: "memory");

#define PH(BUF, KK, STG_STMT, VM_STMT) { \
    bf16x8 af[4], bq[4]; \
    _Pragma("unroll") for (int i = 0; i < 4; i++) { \
      int row = wr + i * 16 + m16; \
      af[i] = *(const bf16x8*)(&As[(BUF) * 8192 + row * 64 + (((KK) * 4 + quad) ^ (row & 7)) * 8]); } \
    _Pragma("unroll") for (int j = 0; j < 4; j++) { \
      int row = wc + j * 16 + m16; \
      bq[j] = *(const bf16x8*)(&Bs[(BUF) * 16384 + row * 64 + (((KK) * 4 + quad) ^ (row & 7)) * 8]); } \
    STG_STMT \
    __builtin_amdgcn_s_barrier(); \
    __builtin_amdgcn_s_setprio(1); \
    _Pragma("unroll") for (int i = 0; i < 4; i++) { \
      _Pragma("unroll") for (int j = 0; j < 4; j++) { \
        acc[i][j] = __builtin_amdgcn_mfma_f32_16x16x32_bf16(af[i], bq[j], acc[i][j], 0, 0, 0); } } \
    __builtin_amdgcn_s_setprio(0); \
    VM_STMT \
    __builtin_amdgcn_s_barrier(); }

#define TILE_FULL(BUF, NBUF, T) \
    PH(BUF, 0, { STGA(NBUF, (T) + 2); STGB(NBUF, (T) + 2, 0); }, ) \
    PH(BUF, 1, { STGB(NBUF, (T) + 2, 1); STGB(NBUF, (T) + 2, 2); STGB(NBUF, (T) + 2, 3); }, VM6)

  // prologue: stage tiles 0 and 1 fully; drain tile 0 (vmcnt(6) leaves tile 1 in flight)
  STGA(0, 0) STGB(0, 0, 0) STGB(0, 0, 1) STGB(0, 0, 2) STGB(0, 0, 3)
  STGA(1, 1) STGB(1, 1, 0) STGB(1, 1, 1) STGB(1, 1, 2) STGB(1, 1, 3)
  VM6
  __builtin_amdgcn_s_barrier();

  int nt = K >> 6;                 // requires nt % 3 == 1, nt >= 7 (K=1024 -> nt=16)
  for (int tk = 0; tk < nt - 4; tk += 3) {
    TILE_FULL(0, 2, tk)
    TILE_FULL(1, 0, tk + 1)
    TILE_FULL(2, 1, tk + 2)
  }
  TILE_FULL(0, 2, nt - 4)          // u = nt-4: stages tile nt-2 into buf2
  TILE_FULL(1, 0, nt - 3)          // u = nt-3: stages tile nt-1 into buf0; vm6 drains nt-2
  PH(2, 0, , )                     // u = nt-2 (buf2)
  PH(2, 1, , VM0)                  //   drain tile nt-1 before its reads
  PH(0, 0, , )                     // u = nt-1 (buf0)
  PH(0, 1, , )

#undef TILE_FULL
#undef PH
#undef VM6
#undef VM0
#undef STGB
#undef STGA

  #pragma unroll
  for (int i = 0; i < 4; i++)
    #pragma unroll
    for (int j = 0; j < 4; j++)
      #pragma unroll
      for (int r = 0; r < 4; r++) {
        size_t row = (size_t)bm * 128 + wr + i * 16 + quad * 4 + r;
        size_t col = (size_t)bn * 256 + wc + j * 16 + m16;
        float v = acc[i][j][r];
        if (OUTF) ((float*)C)[row * N + col] = v;
        else      ((bf16*)C)[row * N + col] = (bf16)v;
      }
}

// ---------------- attention: one block per (bw,h), 8 waves; RoPE fused; causal skip ----------------
// q-tile index qi: only score tiles 0..qi+1 are (partially) visible; only the
// diagonal tile tl==qi+1 needs masking, with the position-independent pattern
// m16 > quad*4+r. Wave balance: qi = {wv, 15-wv, 16+wv, 31-wv} -> 70 tile-units
// per wave for every wv. All guards are wave-uniform -> s_cbranch, and the
// score array s[33] keeps static indexing (no scratch spill).
__global__ __launch_bounds__(512) void attn_kernel(const bf16* __restrict__ qkv,
                                                   const bf16* __restrict__ pmbf,
                                                   const float2* __restrict__ tab,
                                                   bf16* __restrict__ ob) {
  __shared__ bf16 Ks[528 * 72];          // K rows (rope'd), padded stride 72
  __shared__ bf16 Vt[64 * 536 + 16];     // V transposed [d][j], stride 536, zero-padded tail
  __shared__ bf16 Pb[8 * 16 * 40];       // per-wave P staging, stride 40
  int bh = blockIdx.x;
  int bw = bh >> 4, h = bh & 15;
  int seg = bw & 7;
  int t = threadIdx.x;
  int wv = t >> 6, lane = t & 63;
  int m16 = lane & 15, quad = lane >> 4;
  const bf16* qk_base = qkv + (size_t)bw * 512 * 3072 + h * 64;  // row s at +s*3072; K +1024; V +2048
  // stage K rows (pm rows 0..15 unroped, seq rows 16..527 roped at global pos)
  for (int ch = t; ch < 4224; ch += 512) {
    int row = ch >> 3, d0 = (ch & 7) * 8;
    bf16 tmp[8];
    if (row < 16) {
      *(uint4*)tmp = *(const uint4*)(pmbf + ((size_t)h * 16 + row) * 64 + d0);
    } else {
      int s = row - 16;
      *(uint4*)tmp = *(const uint4*)(qk_base + (size_t)s * 3072 + 1024 + d0);
      int pos = seg * 512 + s;
      const float2* tb = tab + pos * 32 + (d0 >> 1);
      #pragma unroll
      for (int p = 0; p < 4; p++) {
        float2 cs = tb[p];
        float x0 = (float)tmp[2 * p], x1 = (float)tmp[2 * p + 1];
        tmp[2 * p]     = (bf16)(x0 * cs.x - x1 * cs.y);
        tmp[2 * p + 1] = (bf16)(x1 * cs.x + x0 * cs.y);
      }
    }
    *(uint4*)(&Ks[row * 72 + d0]) = *(uint4*)tmp;
  }
  // stage V transposed (no rope)
  for (int ch = t; ch < 4224; ch += 512) {
    int row = ch >> 3, d0 = (ch & 7) * 8;
    bf16 tmp[8];
    if (row < 16) *(uint4*)tmp = *(const uint4*)(pmbf + ((size_t)(16 + h) * 16 + row) * 64 + d0);
    else          *(uint4*)tmp = *(const uint4*)(qk_base + (size_t)(row - 16) * 3072 + 2048 + d0);
    #pragma unroll
    for (int i = 0; i < 8; i++) Vt[(d0 + i) * 536 + row] = tmp[i];
  }
  // zero-pad Vt cols 528..535 and the tail so ragged chunks read finite zeros
  if (t < 512) { int r = t >> 3, cc = 528 + (t & 7); Vt[r * 536 + cc] = (bf16)0.f; }
  if (t < 16) Vt[64 * 536 + t] = (bf16)0.f;
  __syncthreads();

  bf16* myP = &Pb[wv * 16 * 40];
  for (int pass = 0; pass < 4; pass++) {
    int qi = (pass == 0) ? wv : (pass == 1) ? 15 - wv : (pass == 2) ? 16 + wv : 31 - wv;
    int q0 = qi * 16;
    int ntl = qi + 2;                       // visible score tiles: 0..qi+1
    int qrow = q0 + m16;
    int pos = seg * 512 + qrow;
    const bf16* qp = qk_base + (size_t)qrow * 3072;
    // load Q frags + rope + 1/8 scale in registers
    bf16 qr0[8], qr1[8];
    *(uint4*)qr0 = *(const uint4*)(qp + quad * 8);
    *(uint4*)qr1 = *(const uint4*)(qp + 32 + quad * 8);
    {
      const float2* tb0 = tab + pos * 32 + quad * 4;
      const float2* tb1 = tb0 + 16;
      #pragma unroll
      for (int p = 0; p < 4; p++) {
        float2 c0 = tb0[p], c1 = tb1[p];
        float a0 = (float)qr0[2 * p], a1 = (float)qr0[2 * p + 1];
        qr0[2 * p]     = (bf16)((a0 * c0.x - a1 * c0.y) * 0.125f);
        qr0[2 * p + 1] = (bf16)((a1 * c0.x + a0 * c0.y) * 0.125f);
        float b0 = (float)qr1[2 * p], b1 = (float)qr1[2 * p + 1];
        qr1[2 * p]     = (bf16)((b0 * c1.x - b1 * c1.y) * 0.125f);
        qr1[2 * p + 1] = (bf16)((b1 * c1.x + b0 * c1.y) * 0.125f);
      }
    }
    bf16x8 qf0 = *(bf16x8*)qr0;
    bf16x8 qf1 = *(bf16x8*)qr1;
    f32x4 s[33];
    #pragma unroll
    for (int tl = 0; tl < 33; tl++) {
      if (tl < ntl) {                       // wave-uniform guard
        f32x4 acc = {0.f, 0.f, 0.f, 0.f};
        bf16x8 b0 = *(const bf16x8*)(&Ks[(tl * 16 + m16) * 72 + quad * 8]);
        bf16x8 b1 = *(const bf16x8*)(&Ks[(tl * 16 + m16) * 72 + 32 + quad * 8]);
        acc = __builtin_amdgcn_mfma_f32_16x16x32_bf16(qf0, b0, acc, 0, 0, 0);
        acc = __builtin_amdgcn_mfma_f32_16x16x32_bf16(qf1, b1, acc, 0, 0, 0);
        if (tl == qi + 1) {                 // diagonal tile: mask m16 > quad*4+r
          #pragma unroll
          for (int r = 0; r < 4; r++)
            if (m16 > quad * 4 + r) acc[r] = -1e30f;
        }
        s[tl] = acc;
      }
    }
    // softmax over visible tiles + 16 lanes of the column group
    float lrow[4];
    #pragma unroll
    for (int r = 0; r < 4; r++) {
      float mx = s[0][r];
      #pragma unroll
      for (int tl = 1; tl < 33; tl++) if (tl < ntl) mx = fmaxf(mx, s[tl][r]);
      mx = fmaxf(mx, __shfl_xor(mx, 1, 64));
      mx = fmaxf(mx, __shfl_xor(mx, 2, 64));
      mx = fmaxf(mx, __shfl_xor(mx, 4, 64));
      mx = fmaxf(mx, __shfl_xor(mx, 8, 64));
      float sum = 0.f;
      #pragma unroll
      for (int tl = 0; tl < 33; tl++) {
        if (tl < ntl) {
          float p = exp2f((s[tl][r] - mx) * LOG2E);
          s[tl][r] = p;
          sum += p;
        }
      }
      sum += __shfl_xor(sum, 1, 64);
      sum += __shfl_xor(sum, 2, 64);
      sum += __shfl_xor(sum, 4, 64);
      sum += __shfl_xor(sum, 8, 64);
      lrow[r] = sum;
    }
    // PV over visible chunks of 32 kv (ragged tail zero-filled)
    f32x4 o[4] = {};
    #pragma unroll
    for (int c = 0; c < 17; c++) {
      if (2 * c < ntl) {                    // wave-uniform guard
        #pragma unroll
        for (int half = 0; half < 2; half++) {
          int tl = 2 * c + half;
          #pragma unroll
          for (int r = 0; r < 4; r++) {
            float pv = (tl < ntl) ? s[tl][r] : 0.f;
            myP[(quad * 4 + r) * 40 + half * 16 + m16] = (bf16)pv;
          }
        }
        asm volatile("s_waitcnt lgkmcnt(0)" ::: "memory");   // wave-local: writes visible
        bf16x8 pf = *(const bf16x8*)(&myP[m16 * 40 + quad * 8]);
        #pragma unroll
        for (int dt = 0; dt < 4; dt++) {
          bf16x8 vf = *(const bf16x8*)(&Vt[(dt * 16 + m16) * 536 + c * 32 + quad * 8]);
          o[dt] = __builtin_amdgcn_mfma_f32_16x16x32_bf16(pf, vf, o[dt], 0, 0, 0);
        }
        asm volatile("s_waitcnt lgkmcnt(0)" ::: "memory");   // reads done before next overwrite
      }
    }
    // normalize + write to [8192][1024] merged layout
    float invl[4];
    #pragma unroll
    for (int r = 0; r < 4; r++) invl[r] = 1.0f / lrow[r];
    #pragma unroll
    for (int dt = 0; dt < 4; dt++)
      #pragma unroll
      for (int r = 0; r < 4; r++) {
        size_t row = (size_t)bw * 512 + q0 + quad * 4 + r;
        ob[row * 1024 + h * 64 + dt * 16 + m16] = (bf16)(o[dt][r] * invl[r]);
      }
  }
}

// ---------------- launch ----------------
extern "C" void kernel_launch(void* const* d_in, const int* in_sizes, int n_in,
                              void* d_out, int out_size, void* d_ws, size_t ws_size,
                              hipStream_t stream) {
  const float* seq  = (const float*)d_in[0];
  const float* g    = (const float*)d_in[1];
  const float* wqkv = (const float*)d_in[2];
  const float* wout = (const float*)d_in[3];
  const float* pm   = (const float*)d_in[4];
  float* out = (float*)d_out;
  char* ws = (char*)d_ws;
  bf16*   wqkv_bf = (bf16*)(ws);                  //  6,291,456
  bf16*   wout_bf = (bf16*)(ws + 6291456);        //  2,097,152
  bf16*   pm_bf   = (bf16*)(ws + 8388608);        //     65,536
  float2* tab     = (float2*)(ws + 8454144);      //  1,048,576 (4096 x 32 cos/sin)
  bf16*   x_bf    = (bf16*)(ws + 9502720);        // 16,777,216 (RMSNorm out, reused as attn out)
  bf16*   qkv_bf  = (bf16*)(ws + 26279936);       // 50,331,648 -> 76,611,584 total

  cast3_kernel<<<4640, 256, 0, stream>>>(wqkv, 786432, wqkv_bf,
                                         wout, 262144, wout_bf,
                                         pm, 8192, pm_bf,
                                         tab, 131072);
  rmsnorm_kernel<<<8192, 256, 0, stream>>>(seq, g, x_bf);
  gemm128x256_kernel<0><<<dim3(12, 64), 512, 0, stream>>>(x_bf, wqkv_bf, qkv_bf, 8192, 3072, 1024);
  attn_kernel<<<256, 512, 0, stream>>>(qkv_bf, pm_bf, tab, x_bf);
  gemm128x256_kernel<1><<<dim3(4, 64), 512, 0, stream>>>(x_bf, wout_bf, out, 8192, 1024, 1024);
}

// Round 3
// 225.017 us; speedup vs baseline: 1.0801x; 1.0801x over previous
//
#include <hip/hip_runtime.h>

typedef __bf16 bf16;
typedef __bf16 bf16x4 __attribute__((ext_vector_type(4)));
typedef __bf16 bf16x8 __attribute__((ext_vector_type(8)));
typedef float f32x4 __attribute__((ext_vector_type(4)));

#define LOG2E 1.44269504088896f

// async global->LDS, 16B per lane. LDS dest is wave-uniform base + lane*16
// (m104/m108): pass the lane-0 pointer; generic->AS(3) = low-32-bit truncation.
__device__ __forceinline__ void gl_lds16(const bf16* g, bf16* l) {
  __builtin_amdgcn_global_load_lds(
      reinterpret_cast<const __attribute__((address_space(1))) void*>((uintptr_t)g),
      reinterpret_cast<__attribute__((address_space(3))) void*>((uint32_t)(uintptr_t)l),
      16, 0, 0);
}

// ---------------- cast fp32 -> bf16 for weights + pm, and build RoPE cos/sin table ----------------
__global__ void cast3_kernel(const float* __restrict__ a, int na4, bf16* __restrict__ oa,
                             const float* __restrict__ b, int nb4, bf16* __restrict__ ob,
                             const float* __restrict__ c, int nc4, bf16* __restrict__ oc,
                             float2* __restrict__ tab, int nt) {
  int i = blockIdx.x * blockDim.x + threadIdx.x;
  if (i < na4 + nb4 + nc4) {
    const float* src; bf16* dst; int idx;
    if (i < na4)            { src = a; dst = oa; idx = i; }
    else if (i < na4 + nb4) { src = b; dst = ob; idx = i - na4; }
    else                    { src = c; dst = oc; idx = i - na4 - nb4; }
    float4 v = ((const float4*)src)[idx];
    bf16x4 o = { (bf16)v.x, (bf16)v.y, (bf16)v.z, (bf16)v.w };
    ((bf16x4*)dst)[idx] = o;
  } else {
    int idx = i - (na4 + nb4 + nc4);
    if (idx >= nt) return;
    int pos = idx >> 5, fi = idx & 31;
    float inv = exp2f((float)fi * -0.41524101186f);   // 10000^(-fi/32)
    float th = (float)pos * inv;
    float sn, cs;
    sincosf(th, &sn, &cs);
    tab[idx] = make_float2(cs, sn);
  }
}

// ---------------- RMSNorm: seq fp32 [8192][1024] -> x bf16 ----------------
__global__ __launch_bounds__(256) void rmsnorm_kernel(const float* __restrict__ seq,
                                                      const float* __restrict__ g,
                                                      bf16* __restrict__ xbf) {
  int row = blockIdx.x;
  int t = threadIdx.x;
  float4 x = ((const float4*)(seq + (size_t)row * 1024))[t];
  float ss = x.x*x.x + x.y*x.y + x.z*x.z + x.w*x.w;
  #pragma unroll
  for (int m = 32; m >= 1; m >>= 1) ss += __shfl_xor(ss, m, 64);
  __shared__ float red[4];
  if ((t & 63) == 0) red[t >> 6] = ss;
  __syncthreads();
  float tot = red[0] + red[1] + red[2] + red[3];
  float scale = rsqrtf(tot * (1.0f / 1024.0f) + 1.1920929e-07f);
  float4 gv = ((const float4*)g)[t];
  bf16x4 o = { (bf16)(x.x*scale*gv.x), (bf16)(x.y*scale*gv.y),
               (bf16)(x.z*scale*gv.z), (bf16)(x.w*scale*gv.w) };
  ((bf16x4*)(xbf + (size_t)row * 1024))[t] = o;
}

// ---------------- 128x256 8-wave pipelined GEMM, C[M,N] = A[M,K] * B[N,K]^T ----------------
// Perfect grid packing: (N/256) x (M/128) blocks (768 for QKV = 3/CU, 256 for out-proj).
// Triple-buffered LDS (144 KiB), DMA 2 tiles ahead (6 gl_lds16/tile), one counted
// vmcnt(6) per tile.  NEW vs round 2: register-level software pipeline — frag reads
// for phase p+1 are issued BEFORE phase p's MFMA block (double reg set afA/bqA |
// afB/bqB), so the LDS pipe delivers next-phase frags WHILE the matrix pipe runs.
// MFMA waits only on the older read set via compiler-counted lgkmcnt(8).
// sched_barrier(0) pins the read/MFMA order against compiler re-serialization.
// Schedule per steady tile u (cur=u%3, nxt=(u+1)%3, dmab=(u+2)%3):
//   DMA6(dmab, u+2); RD_B(cur,kk1); MM(A); vmcnt(6); barrier;   // publishes tile u+1
//   RD_A(nxt,kk0);   MM(B);         barrier;                    // WAR fence for buf cur
// Lifetimes verified: DMA into buf b (tile b+1 top) is after exit barrier of tile b,
// whose reads completed before MM(B) of tile b; reads of tile u+1 data only occur
// after tile u's vmcnt(6)+barrier.  Tail: vmcnt(0) before tile nt-1's reads.
// Requires nt = K/64, nt % 3 == 1, nt >= 7 (K=1024 -> nt=16).
template<int OUTF>
__global__ __launch_bounds__(512) void gemm128x256_kernel(const bf16* __restrict__ A,
                                                          const bf16* __restrict__ B,
                                                          void* __restrict__ C,
                                                          int M, int N, int K) {
  __shared__ bf16 As[3 * 8192];    // [buf][128 rows][64 k], XOR-swizzled chunks
  __shared__ bf16 Bs[3 * 16384];   // [buf][256 rows][64 k]
  int t = threadIdx.x;
  int lane = t & 63, wv = t >> 6;
  int m16 = lane & 15, quad = lane >> 4;
  int wr = (wv >> 2) * 64, wc = (wv & 3) * 64;   // 2M x 4N waves, per-wave C = 64x64
  int bn = blockIdx.x, bm = blockIdx.y;
  const bf16* Ab = A + (size_t)bm * 128 * K;
  const bf16* Bb = B + (size_t)bn * 256 * K;
  // per-lane pre-swizzled global source offsets: LDS chunk s (16B) of a tile holds
  // global k-chunk (s&7)^(row&7) of row s>>3 (row-major, 8 chunks of 8 bf16 per row).
  int aoff[2], boff[4];
  #pragma unroll
  for (int l = 0; l < 2; l++) { int s = l * 512 + t; int row = s >> 3; aoff[l] = row * K + ((s & 7) ^ (row & 7)) * 8; }
  #pragma unroll
  for (int l = 0; l < 4; l++) { int s = l * 512 + t; int row = s >> 3; boff[l] = row * K + ((s & 7) ^ (row & 7)) * 8; }
  f32x4 acc[4][4] = {};
  bf16x8 afA[4], bqA[4], afB[4], bqB[4];   // double-buffered frag registers

#define STGA(BUF, T) { int k0 = (T) * 64; \
    gl_lds16(Ab + k0 + aoff[0], &As[(BUF) * 8192 + wv * 512]); \
    gl_lds16(Ab + k0 + aoff[1], &As[(BUF) * 8192 + 4096 + wv * 512]); }
#define STGB(BUF, T, L) { int k0 = (T) * 64; \
    gl_lds16(Bb + k0 + boff[L], &Bs[(BUF) * 16384 + (L) * 4096 + wv * 512]); }
#define DMA6(BUF, T) { STGA(BUF, T) STGB(BUF, T, 0) STGB(BUF, T, 1) STGB(BUF, T, 2) STGB(BUF, T, 3) }
#define VM6 asm volatile("s_waitcnt vmcnt(6)" ::: "memory");
#define VM0 asm volatile("s_waitcnt vmcnt(0)" ::: "memory");
#define BAR __builtin_amdgcn_s_barrier();
#define SB0 __builtin_amdgcn_sched_barrier(0);

#define RD(AF, BQ, BUF, KK) { \
    _Pragma("unroll") for (int i = 0; i < 4; i++) { \
      int row = wr + i * 16 + m16; \
      AF[i] = *(const bf16x8*)(&As[(BUF) * 8192 + row * 64 + (((KK) * 4 + quad) ^ (row & 7)) * 8]); } \
    _Pragma("unroll") for (int j = 0; j < 4; j++) { \
      int row = wc + j * 16 + m16; \
      BQ[j] = *(const bf16x8*)(&Bs[(BUF) * 16384 + row * 64 + (((KK) * 4 + quad) ^ (row & 7)) * 8]); } }

#define MM(AF, BQ) { \
    _Pragma("unroll") for (int i = 0; i < 4; i++) { \
      _Pragma("unroll") for (int j = 0; j < 4; j++) { \
        acc[i][j] = __builtin_amdgcn_mfma_f32_16x16x32_bf16(AF[i], BQ[j], acc[i][j], 0, 0, 0); } } }

#define TILE_STEADY(CUR, NXT, DMAB, T) { \
    DMA6(DMAB, (T) + 2) \
    RD(afB, bqB, CUR, 1) SB0 \
    MM(afA, bqA) \
    VM6 BAR SB0 \
    RD(afA, bqA, NXT, 0) SB0 \
    MM(afB, bqB) \
    BAR SB0 }

  // prologue: stage tiles 0,1; publish tile 0; preload phase-0 frags
  DMA6(0, 0) DMA6(1, 1)
  VM6                              // drain tile 0's 6 (tile 1's stay in flight)
  BAR SB0
  RD(afA, bqA, 0, 0) SB0

  int nt = K >> 6;                 // nt % 3 == 1, nt >= 7
  for (int tk = 0; tk < nt - 4; tk += 3) {
    TILE_STEADY(0, 1, 2, tk)
    TILE_STEADY(1, 2, 0, tk + 1)
    TILE_STEADY(2, 0, 1, tk + 2)
  }
  TILE_STEADY(0, 1, 2, nt - 4)     // stages tile nt-2 -> buf2
  TILE_STEADY(1, 2, 0, nt - 3)     // stages tile nt-1 -> buf0; vm6 publishes nt-2
  // tile nt-2 (cur=2, nxt=0): no DMA; drain tile nt-1 fully before its reads
  RD(afB, bqB, 2, 1) SB0
  MM(afA, bqA)
  VM0 BAR SB0
  RD(afA, bqA, 0, 0) SB0
  MM(afB, bqB)
  BAR SB0
  // tile nt-1 (cur=0): final tile, no staging, no barriers needed after
  RD(afB, bqB, 0, 1) SB0
  MM(afA, bqA)
  MM(afB, bqB)

#undef TILE_STEADY
#undef MM
#undef RD
#undef SB0
#undef BAR
#undef VM0
#undef VM6
#undef DMA6
#undef STGB
#undef STGA

  #pragma unroll
  for (int i = 0; i < 4; i++)
    #pragma unroll
    for (int j = 0; j < 4; j++)
      #pragma unroll
      for (int r = 0; r < 4; r++) {
        size_t row = (size_t)bm * 128 + wr + i * 16 + quad * 4 + r;
        size_t col = (size_t)bn * 256 + wc + j * 16 + m16;
        float v = acc[i][j][r];
        if (OUTF) ((float*)C)[row * N + col] = v;
        else      ((bf16*)C)[row * N + col] = (bf16)v;
      }
}

// ---------------- attention: one block per (bw,h), 8 waves; RoPE fused; causal skip ----------------
// q-tile index qi: only score tiles 0..qi+1 are (partially) visible; only the
// diagonal tile tl==qi+1 needs masking, with the position-independent pattern
// m16 > quad*4+r. Wave balance: qi = {wv, 15-wv, 16+wv, 31-wv} -> 70 tile-units
// per wave for every wv. All guards are wave-uniform -> s_cbranch, and the
// score array s[33] keeps static indexing (no scratch spill).
__global__ __launch_bounds__(512) void attn_kernel(const bf16* __restrict__ qkv,
                                                   const bf16* __restrict__ pmbf,
                                                   const float2* __restrict__ tab,
                                                   bf16* __restrict__ ob) {
  __shared__ bf16 Ks[528 * 72];          // K rows (rope'd), padded stride 72
  __shared__ bf16 Vt[64 * 536 + 16];     // V transposed [d][j], stride 536, zero-padded tail
  __shared__ bf16 Pb[8 * 16 * 40];       // per-wave P staging, stride 40
  int bh = blockIdx.x;
  int bw = bh >> 4, h = bh & 15;
  int seg = bw & 7;
  int t = threadIdx.x;
  int wv = t >> 6, lane = t & 63;
  int m16 = lane & 15, quad = lane >> 4;
  const bf16* qk_base = qkv + (size_t)bw * 512 * 3072 + h * 64;  // row s at +s*3072; K +1024; V +2048
  // stage K rows (pm rows 0..15 unroped, seq rows 16..527 roped at global pos)
  for (int ch = t; ch < 4224; ch += 512) {
    int row = ch >> 3, d0 = (ch & 7) * 8;
    bf16 tmp[8];
    if (row < 16) {
      *(uint4*)tmp = *(const uint4*)(pmbf + ((size_t)h * 16 + row) * 64 + d0);
    } else {
      int s = row - 16;
      *(uint4*)tmp = *(const uint4*)(qk_base + (size_t)s * 3072 + 1024 + d0);
      int pos = seg * 512 + s;
      const float2* tb = tab + pos * 32 + (d0 >> 1);
      #pragma unroll
      for (int p = 0; p < 4; p++) {
        float2 cs = tb[p];
        float x0 = (float)tmp[2 * p], x1 = (float)tmp[2 * p + 1];
        tmp[2 * p]     = (bf16)(x0 * cs.x - x1 * cs.y);
        tmp[2 * p + 1] = (bf16)(x1 * cs.x + x0 * cs.y);
      }
    }
    *(uint4*)(&Ks[row * 72 + d0]) = *(uint4*)tmp;
  }
  // stage V transposed (no rope)
  for (int ch = t; ch < 4224; ch += 512) {
    int row = ch >> 3, d0 = (ch & 7) * 8;
    bf16 tmp[8];
    if (row < 16) *(uint4*)tmp = *(const uint4*)(pmbf + ((size_t)(16 + h) * 16 + row) * 64 + d0);
    else          *(uint4*)tmp = *(const uint4*)(qk_base + (size_t)(row - 16) * 3072 + 2048 + d0);
    #pragma unroll
    for (int i = 0; i < 8; i++) Vt[(d0 + i) * 536 + row] = tmp[i];
  }
  // zero-pad Vt cols 528..535 and the tail so ragged chunks read finite zeros
  if (t < 512) { int r = t >> 3, cc = 528 + (t & 7); Vt[r * 536 + cc] = (bf16)0.f; }
  if (t < 16) Vt[64 * 536 + t] = (bf16)0.f;
  __syncthreads();

  bf16* myP = &Pb[wv * 16 * 40];
  for (int pass = 0; pass < 4; pass++) {
    int qi = (pass == 0) ? wv : (pass == 1) ? 15 - wv : (pass == 2) ? 16 + wv : 31 - wv;
    int q0 = qi * 16;
    int ntl = qi + 2;                       // visible score tiles: 0..qi+1
    int qrow = q0 + m16;
    int pos = seg * 512 + qrow;
    const bf16* qp = qk_base + (size_t)qrow * 3072;
    // load Q frags + rope + 1/8 scale in registers
    bf16 qr0[8], qr1[8];
    *(uint4*)qr0 = *(const uint4*)(qp + quad * 8);
    *(uint4*)qr1 = *(const uint4*)(qp + 32 + quad * 8);
    {
      const float2* tb0 = tab + pos * 32 + quad * 4;
      const float2* tb1 = tb0 + 16;
      #pragma unroll
      for (int p = 0; p < 4; p++) {
        float2 c0 = tb0[p], c1 = tb1[p];
        float a0 = (float)qr0[2 * p], a1 = (float)qr0[2 * p + 1];
        qr0[2 * p]     = (bf16)((a0 * c0.x - a1 * c0.y) * 0.125f);
        qr0[2 * p + 1] = (bf16)((a1 * c0.x + a0 * c0.y) * 0.125f);
        float b0 = (float)qr1[2 * p], b1 = (float)qr1[2 * p + 1];
        qr1[2 * p]     = (bf16)((b0 * c1.x - b1 * c1.y) * 0.125f);
        qr1[2 * p + 1] = (bf16)((b1 * c1.x + b0 * c1.y) * 0.125f);
      }
    }
    bf16x8 qf0 = *(bf16x8*)qr0;
    bf16x8 qf1 = *(bf16x8*)qr1;
    f32x4 s[33];
    #pragma unroll
    for (int tl = 0; tl < 33; tl++) {
      if (tl < ntl) {                       // wave-uniform guard
        f32x4 acc = {0.f, 0.f, 0.f, 0.f};
        bf16x8 b0 = *(const bf16x8*)(&Ks[(tl * 16 + m16) * 72 + quad * 8]);
        bf16x8 b1 = *(const bf16x8*)(&Ks[(tl * 16 + m16) * 72 + 32 + quad * 8]);
        acc = __builtin_amdgcn_mfma_f32_16x16x32_bf16(qf0, b0, acc, 0, 0, 0);
        acc = __builtin_amdgcn_mfma_f32_16x16x32_bf16(qf1, b1, acc, 0, 0, 0);
        if (tl == qi + 1) {                 // diagonal tile: mask m16 > quad*4+r
          #pragma unroll
          for (int r = 0; r < 4; r++)
            if (m16 > quad * 4 + r) acc[r] = -1e30f;
        }
        s[tl] = acc;
      }
    }
    // softmax over visible tiles + 16 lanes of the column group
    float lrow[4];
    #pragma unroll
    for (int r = 0; r < 4; r++) {
      float mx = s[0][r];
      #pragma unroll
      for (int tl = 1; tl < 33; tl++) if (tl < ntl) mx = fmaxf(mx, s[tl][r]);
      mx = fmaxf(mx, __shfl_xor(mx, 1, 64));
      mx = fmaxf(mx, __shfl_xor(mx, 2, 64));
      mx = fmaxf(mx, __shfl_xor(mx, 4, 64));
      mx = fmaxf(mx, __shfl_xor(mx, 8, 64));
      float sum = 0.f;
      #pragma unroll
      for (int tl = 0; tl < 33; tl++) {
        if (tl < ntl) {
          float p = exp2f((s[tl][r] - mx) * LOG2E);
          s[tl][r] = p;
          sum += p;
        }
      }
      sum += __shfl_xor(sum, 1, 64);
      sum += __shfl_xor(sum, 2, 64);
      sum += __shfl_xor(sum, 4, 64);
      sum += __shfl_xor(sum, 8, 64);
      lrow[r] = sum;
    }
    // PV over visible chunks of 32 kv (ragged tail zero-filled)
    f32x4 o[4] = {};
    #pragma unroll
    for (int c = 0; c < 17; c++) {
      if (2 * c < ntl) {                    // wave-uniform guard
        #pragma unroll
        for (int half = 0; half < 2; half++) {
          int tl = 2 * c + half;
          #pragma unroll
          for (int r = 0; r < 4; r++) {
            float pv = (tl < ntl) ? s[tl][r] : 0.f;
            myP[(quad * 4 + r) * 40 + half * 16 + m16] = (bf16)pv;
          }
        }
        asm volatile("s_waitcnt lgkmcnt(0)" ::: "memory");   // wave-local: writes visible
        bf16x8 pf = *(const bf16x8*)(&myP[m16 * 40 + quad * 8]);
        #pragma unroll
        for (int dt = 0; dt < 4; dt++) {
          bf16x8 vf = *(const bf16x8*)(&Vt[(dt * 16 + m16) * 536 + c * 32 + quad * 8]);
          o[dt] = __builtin_amdgcn_mfma_f32_16x16x32_bf16(pf, vf, o[dt], 0, 0, 0);
        }
        asm volatile("s_waitcnt lgkmcnt(0)" ::: "memory");   // reads done before next overwrite
      }
    }
    // normalize + write to [8192][1024] merged layout
    float invl[4];
    #pragma unroll
    for (int r = 0; r < 4; r++) invl[r] = 1.0f / lrow[r];
    #pragma unroll
    for (int dt = 0; dt < 4; dt++)
      #pragma unroll
      for (int r = 0; r < 4; r++) {
        size_t row = (size_t)bw * 512 + q0 + quad * 4 + r;
        ob[row * 1024 + h * 64 + dt * 16 + m16] = (bf16)(o[dt][r] * invl[r]);
      }
  }
}

// ---------------- launch ----------------
extern "C" void kernel_launch(void* const* d_in, const int* in_sizes, int n_in,
                              void* d_out, int out_size, void* d_ws, size_t ws_size,
                              hipStream_t stream) {
  const float* seq  = (const float*)d_in[0];
  const float* g    = (const float*)d_in[1];
  const float* wqkv = (const float*)d_in[2];
  const float* wout = (const float*)d_in[3];
  const float* pm   = (const float*)d_in[4];
  float* out = (float*)d_out;
  char* ws = (char*)d_ws;
  bf16*   wqkv_bf = (bf16*)(ws);                  //  6,291,456
  bf16*   wout_bf = (bf16*)(ws + 6291456);        //  2,097,152
  bf16*   pm_bf   = (bf16*)(ws + 8388608);        //     65,536
  float2* tab     = (float2*)(ws + 8454144);      //  1,048,576 (4096 x 32 cos/sin)
  bf16*   x_bf    = (bf16*)(ws + 9502720);        // 16,777,216 (RMSNorm out, reused as attn out)
  bf16*   qkv_bf  = (bf16*)(ws + 26279936);       // 50,331,648 -> 76,611,584 total

  cast3_kernel<<<4640, 256, 0, stream>>>(wqkv, 786432, wqkv_bf,
                                         wout, 262144, wout_bf,
                                         pm, 8192, pm_bf,
                                         tab, 131072);
  rmsnorm_kernel<<<8192, 256, 0, stream>>>(seq, g, x_bf);
  gemm128x256_kernel<0><<<dim3(12, 64), 512, 0, stream>>>(x_bf, wqkv_bf, qkv_bf, 8192, 3072, 1024);
  attn_kernel<<<256, 512, 0, stream>>>(qkv_bf, pm_bf, tab, x_bf);
  gemm128x256_kernel<1><<<dim3(4, 64), 512, 0, stream>>>(x_bf, wout_bf, out, 8192, 1024, 1024);
}